// Round 11
// baseline (129.246 us; speedup 1.0000x reference)
//
#include <hip/hip_runtime.h>
#include <math.h>

#define Bb 8
#define Cc 64
#define Nn 256
#define FD 128
#define SEGS 4
#define ROWS 64          // rows per block
#define TILE (Nn * FD)   // 32768 floats per (b,c)

typedef float floatx4 __attribute__((ext_vector_type(4)));

// ---------------------------------------------------------------------------
// s1: one block per (bc, seg) — 64 rows, single pass, in-loop mask fold,
// 16-LANE ROW GROUPS (8 floats/lane), COALESCED lane->float4 mapping.
//
// Coalescing fix (r11): lane l16 now loads float4 indices {l16, l16+16}
// instead of {2*l16, 2*l16+1}. Each global_load_dwordx4 instruction then
// covers a contiguous 256 B (16 lanes x 16 B dense) instead of a 512 B
// span at 32 B stride half-used. Same HBM traffic, fewer VMEM/L1 sector
// cycles. All consumers (dots, rs, rss, 16-lane butterfly) are invariant
// to this permutation since operand slices use the SAME mapping.
//
// Accumulator scheme (r9): mask folded in-loop; query side reconstructed
// from unconditional totals in s2f (q = tot - m). bpart slots:
// [0]=Σm ds, [1]=Σq dq, [2]=Σm rs, [3]=Σtot rs, [4]=Σm rss, [5]=Σtot rss,
// ([6],[7]=ss,qq on seg0). __launch_bounds__(256,2) guards the 32-VGPR
// remat pathology (r4/r5).
// ---------------------------------------------------------------------------
__global__ __launch_bounds__(256, 2) void s1(
    const float* __restrict__ h, const float* __restrict__ op,
    const float* __restrict__ opS, const float* __restrict__ opQ,
    unsigned long long* __restrict__ maskbuf, float* __restrict__ bpart) {
  const int blk = blockIdx.x;
  const int bc = blk >> 2, seg = blk & 3;
  const int c = bc & (Cc - 1);
  const float* __restrict__ tile = h + (size_t)bc * TILE;
  const int tid = threadIdx.x, lane = tid & 63, wv = tid >> 6;
  const int g = tid >> 4, l16 = tid & 15;   // 16 groups x 16 lanes

  __shared__ unsigned int s_mb[16];  // 16 groups x 4 row-mask bits
  __shared__ float s_red[4][6];

  // every 16-lane group redundantly computes the source-row dots
  const float4 sv0 = ((const float4*)tile)[l16];
  const float4 sv1 = ((const float4*)tile)[l16 + 16];
  const float4 oc0 = ((const float4*)(op + c * 2 * FD))[l16];
  const float4 oc1 = ((const float4*)(op + c * 2 * FD))[l16 + 16];
  float cs = sv0.x * oc0.x + sv0.y * oc0.y + sv0.z * oc0.z + sv0.w * oc0.w
           + sv1.x * oc1.x + sv1.y * oc1.y + sv1.z * oc1.z + sv1.w * oc1.w;
  float ssv = 0.0f, qqv = 0.0f;
  if (seg == 0) {   // softmax source dots, once per (b,c)
    const float4 os0 = ((const float4*)(opS + c * 2 * FD + FD))[l16];
    const float4 os1 = ((const float4*)(opS + c * 2 * FD + FD))[l16 + 16];
    const float4 oq0 = ((const float4*)(opQ + c * 2 * FD + FD))[l16];
    const float4 oq1 = ((const float4*)(opQ + c * 2 * FD + FD))[l16 + 16];
    ssv = sv0.x * os0.x + sv0.y * os0.y + sv0.z * os0.z + sv0.w * os0.w
        + sv1.x * os1.x + sv1.y * os1.y + sv1.z * os1.z + sv1.w * os1.w;
    qqv = sv0.x * oq0.x + sv0.y * oq0.y + sv0.z * oq0.z + sv0.w * oq0.w
        + sv1.x * oq1.x + sv1.y * oq1.y + sv1.z * oq1.z + sv1.w * oq1.w;
  }
#pragma unroll
  for (int off = 8; off >= 1; off >>= 1) {   // stays within 16-lane group
    cs  += __shfl_xor(cs,  off, 64);
    ssv += __shfl_xor(ssv, off, 64);
    qqv += __shfl_xor(qqv, off, 64);
  }

  // operand slices: this lane's 8 floats of each operator vector
  const float4 oH0 = ((const float4*)(op  + c * 2 * FD + FD))[l16];
  const float4 oH1 = ((const float4*)(op  + c * 2 * FD + FD))[l16 + 16];
  const float4 oS0 = ((const float4*)(opS + c * 2 * FD))[l16];
  const float4 oS1 = ((const float4*)(opS + c * 2 * FD))[l16 + 16];
  const float4 oQ0 = ((const float4*)(opQ + c * 2 * FD))[l16];
  const float4 oQ1 = ((const float4*)(opQ + c * 2 * FD))[l16 + 16];

  float a_dsm = 0, a_dqq = 0, a_rsm = 0, a_rst = 0, a_rssm = 0, a_rsst = 0;
  unsigned int mbits = 0;

  // 16 groups x 4 rows = 64 rows; each lane covers 8 floats of its row.
#pragma unroll
  for (int i = 0; i < 4; ++i) {
    const int row = g * 4 + i;
    const float4* rp4 = (const float4*)(tile + (size_t)(seg * ROWS + row) * FD);
    const float4 v0 = rp4[l16];
    const float4 v1 = rp4[l16 + 16];
    float dh = v0.x * oH0.x + v0.y * oH0.y + v0.z * oH0.z + v0.w * oH0.w
             + v1.x * oH1.x + v1.y * oH1.y + v1.z * oH1.z + v1.w * oH1.w;
    const float ds = v0.x * oS0.x + v0.y * oS0.y + v0.z * oS0.z + v0.w * oS0.w
                   + v1.x * oS1.x + v1.y * oS1.y + v1.z * oS1.z + v1.w * oS1.w;
    const float dq = v0.x * oQ0.x + v0.y * oQ0.y + v0.z * oQ0.z + v0.w * oQ0.w
                   + v1.x * oQ1.x + v1.y * oQ1.y + v1.z * oQ1.z + v1.w * oQ1.w;
    const float rs  = v0.x + v0.y + v0.z + v0.w + v1.x + v1.y + v1.z + v1.w;
    const float rss = v0.x * v0.x + v0.y * v0.y + v0.z * v0.z + v0.w * v0.w
                    + v1.x * v1.x + v1.y * v1.y + v1.z * v1.z + v1.w * v1.w;
#pragma unroll
    for (int off = 8; off >= 1; off >>= 1) dh += __shfl_xor(dh, off, 64);
    const bool m = (dh + cs) >= 0.0f;       // full row logit in every lane
    a_dsm  += m ? ds  : 0.0f;
    a_dqq  += m ? 0.0f : dq;
    a_rsm  += m ? rs  : 0.0f;
    a_rssm += m ? rss : 0.0f;
    a_rst  += rs;                            // unconditional totals
    a_rsst += rss;
    mbits |= (m ? 1u : 0u) << i;
  }
  if (l16 == 0) s_mb[g] = mbits;

  // block-wide reduction of the 6 partials
#pragma unroll
  for (int off = 32; off >= 1; off >>= 1) {
    a_dsm  += __shfl_xor(a_dsm,  off, 64);
    a_dqq  += __shfl_xor(a_dqq,  off, 64);
    a_rsm  += __shfl_xor(a_rsm,  off, 64);
    a_rst  += __shfl_xor(a_rst,  off, 64);
    a_rssm += __shfl_xor(a_rssm, off, 64);
    a_rsst += __shfl_xor(a_rsst, off, 64);
  }
  if (lane == 0) {
    s_red[wv][0] = a_dsm; s_red[wv][1] = a_dqq;
    s_red[wv][2] = a_rsm; s_red[wv][3] = a_rst;
    s_red[wv][4] = a_rssm; s_red[wv][5] = a_rsst;
  }
  __syncthreads();
  if (tid < 6) {
    bpart[(size_t)blk * 8 + tid] =
        s_red[0][tid] + s_red[1][tid] + s_red[2][tid] + s_red[3][tid];
  }
  // tid 6,7 are in group 0 and hold the full ssv/qqv (group-redundant)
  if (seg == 0 && tid == 6) bpart[(size_t)blk * 8 + 6] = ssv;
  if (seg == 0 && tid == 7) bpart[(size_t)blk * 8 + 7] = qqv;
  if (tid == 0) {
    unsigned long long mk = 0;
#pragma unroll
    for (int k = 0; k < 16; ++k)
      mk |= (unsigned long long)(s_mb[k] & 0xFu) << (4 * k);
    maskbuf[blk] = mk;
  }
}

// ---------------------------------------------------------------------------
// s2f: fused finalize + elementwise. One block per (bc, seg). (proven)
// bpart slots 3,5 are TOTALS; query-side = total - masked.
// ---------------------------------------------------------------------------
__global__ __launch_bounds__(256) void s2f(
    const float* __restrict__ h, const unsigned long long* __restrict__ maskbuf,
    const float* __restrict__ bpart, const float* __restrict__ gamma,
    const float* __restrict__ beta, float* __restrict__ out) {
  const int blk = blockIdx.x, bc = blk >> 2, seg = blk & 3;
  const int c = bc & (Cc - 1), bmine = bc >> 6;
  const int tid = threadIdx.x, lane = tid & 63, hw = tid >> 5, hl = tid & 31;
  __shared__ float s_S[Bb], s_SS[Bb], s_ws[2 * Bb];
  __shared__ float s_a[ROWS];

  const int b = hw;                    // 8 half-waves -> 8 batch entries
  const int bcb = b * Cc + c;

  // combine the 4 seg-partials (lanes hl<6, one j each); hl==6,7 read the
  // seg0-only source dots.
  float aj = 0.0f;
  if (hl < 6) {
#pragma unroll
    for (int k = 0; k < SEGS; ++k)
      aj += bpart[(size_t)(bcb * SEGS + k) * 8 + hl];
  } else if (hl < 8) {
    aj = bpart[(size_t)(bcb * SEGS) * 8 + hl];
  }
  const int base = lane & 32;
  float a0 = __shfl(aj, base + 0, 64), a1 = __shfl(aj, base + 1, 64);
  float a2 = __shfl(aj, base + 2, 64), a3 = __shfl(aj, base + 3, 64);
  float a4 = __shfl(aj, base + 4, 64), a5 = __shfl(aj, base + 5, 64);
  float ss = __shfl(aj, base + 6, 64), qq = __shfl(aj, base + 7, 64);

  float sa = a0 * (1.0f / Nn) + ss;
  float qa = a1 * (1.0f / Nn) + qq;
  float mx = fmaxf(sa, qa);
  float es = __expf(sa - mx), eq = __expf(qa - mx);
  float inv = 1.0f / (es + eq);
  float w_s = es * inv, w_q = eq * inv;
  if (hl == 0) {
    s_S[b]  = w_s * a2 + w_q * (a3 - a2);              // q = tot - m
    s_SS[b] = w_s * w_s * a4 + w_q * w_q * (a5 - a4);  // q = tot - m
    s_ws[2 * b] = w_s; s_ws[2 * b + 1] = w_q;
  }
  __syncthreads();

  // channel stats (all threads redundantly, LDS broadcast reads)
  float S = 0.0f, SS = 0.0f;
#pragma unroll
  for (int k = 0; k < Bb; ++k) { S += s_S[k]; SS += s_SS[k]; }
  const float invcnt = 1.0f / (float)(Bb * Nn * FD);
  const float mean = S * invcnt;
  const float var  = SS * invcnt - mean * mean;
  const float scale = gamma[c] * rsqrtf(var + 1e-5f);
  const float shift = beta[c] - mean * scale;

  if (tid < ROWS) {
    const unsigned long long m = maskbuf[blk];
    const float w = ((m >> tid) & 1ull) ? s_ws[2 * bmine] : s_ws[2 * bmine + 1];
    s_a[tid] = w * scale;
  }
  __syncthreads();

  const float4* __restrict__ h4 = (const float4*)(h + (size_t)bc * TILE) + seg * 2048;
  floatx4* __restrict__ o4 = (floatx4*)(out + (size_t)bc * TILE) + seg * 2048;
#pragma unroll
  for (int k = 0; k < 8; ++k) {
    const int idx = k * 256 + tid;
    const float a = s_a[idx >> 5];   // 32 float4 per row -> broadcast per 32 lanes
    float4 v = h4[idx];
    floatx4 r;
    r.x = fmaf(v.x, a, shift);
    r.y = fmaf(v.y, a, shift);
    r.z = fmaf(v.z, a, shift);
    r.w = fmaf(v.w, a, shift);
    r.x = r.x > 0.0f ? r.x : __expf(r.x) - 1.0f;
    r.y = r.y > 0.0f ? r.y : __expf(r.y) - 1.0f;
    r.z = r.z > 0.0f ? r.z : __expf(r.z) - 1.0f;
    r.w = r.w > 0.0f ? r.w : __expf(r.w) - 1.0f;
    __builtin_nontemporal_store(r, &o4[idx]);
  }
}

extern "C" void kernel_launch(void* const* d_in, const int* in_sizes, int n_in,
                              void* d_out, int out_size, void* d_ws, size_t ws_size,
                              hipStream_t stream) {
  const float* h     = (const float*)d_in[0];
  const float* op    = (const float*)d_in[1];
  const float* opS   = (const float*)d_in[2];
  const float* opQ   = (const float*)d_in[3];
  const float* gamma = (const float*)d_in[4];
  const float* beta  = (const float*)d_in[5];
  float* out = (float*)d_out;

  unsigned long long* maskbuf = (unsigned long long*)d_ws;   // 2048 u64 = 16 KB
  float* bpart = (float*)((char*)d_ws + 16384);              // 2048*8 floats = 64 KB

  s1<<<Bb * Cc * SEGS, 256, 0, stream>>>(h, op, opS, opQ, maskbuf, bpart);
  s2f<<<Bb * Cc * SEGS, 256, 0, stream>>>(h, maskbuf, bpart, gamma, beta, out);
}